// Round 9
// baseline (2073.641 us; speedup 1.0000x reference)
//
#include <hip/hip_runtime.h>
#include <hip/hip_bf16.h>

// EncoderDecoderConvLSTM — Round 19: x-part vectorization + loop/overhead
// ablation. R18 (counted vmcnt) was NULL -> the A-wait chain is not the
// bottleneck, and ~2/3 of block time is unexplained by instruction models.
// This round: (1) wx transposed to [9][256] so the encoder x-part loads
// f32x4 (36 vector loads vs 288 scalar stride-9 loads); (2) one diagnostic
// dispatch lstm_mfma_k<true,2,true>: 18-phase loop run TWICE, stores
// replaced by asm sink (keeps math live, rule #17). loop_time = abl - enc
// decides R20: >=55us -> 32x32-MFMA redesign; <=35us -> persistent rows.
// Everything else identical to R18 (DMA staging, counted vmcnt, pre-swizzled
// W/h, zero-page border, fused epilogue).

#define HW 4096
#define NF 64

typedef __attribute__((ext_vector_type(8))) short bf16x8;
typedef __attribute__((ext_vector_type(4))) float f32x4;

__device__ __forceinline__ float fsig(float v) {
  return __builtin_amdgcn_rcpf(1.f + __expf(-v));
}
__device__ __forceinline__ float ftanh(float v) {
  float vc = fminf(fmaxf(v, -15.f), 15.f);
  float e = __expf(2.f * vc);
  return (e - 1.f) * __builtin_amdgcn_rcpf(e + 1.f);
}
__device__ __forceinline__ float bf2f(short s) {
  union { unsigned u; float f; } a;
  a.u = ((unsigned)(unsigned short)s) << 16;
  return a.f;
}
__device__ __forceinline__ short f2bf(float f) {  // RNE
  union { float f; unsigned u; } a;
  a.f = f;
  unsigned r = (a.u + 0x7fff + ((a.u >> 16) & 1)) >> 16;
  return (short)r;
}
// async 16B/lane global->LDS; lds base must be wave-uniform
__device__ __forceinline__ void dma16(const short* g, short* l) {
  __builtin_amdgcn_global_load_lds(
      (const __attribute__((address_space(1))) char*)g,
      (__attribute__((address_space(3))) char*)l, 16, 0, 0);
}

// 8 waves: wnf = wv&3 (16-oc slice per gate), whalf = wv>>2 (px half).
// LDS: As3[3][8192] rotating gate-pair buffers (pre-swizzled W, linear DMA),
// Bs[3][66][64] halo (slot s = px+1; slots 0/65 zero; content swizzled
// ^(s&7)<<3 via pre-swizzled h_sw), xs[3][64].
// REPS: phase-loop repetitions (diagnostic). SINK: no stores, asm data-sink.
template <bool HAS_X, int REPS, bool SINK>
__global__ __launch_bounds__(512) void lstm_mfma_k(
    const short* __restrict__ hin,   // [32][4096][64] bf16, PRE-SWIZZLED
    const short* __restrict__ W,     // [9][256][64] bf16, pre-swizzled
    const float* __restrict__ wx,    // [9][256] f32 (x-part, tap-major) or null
    const float* __restrict__ xpl,   // x + t*HW (batch stride 12*HW) or null
    const float* __restrict__ bias,  // [256] f32
    const float* __restrict__ cin,   // [32][4096][64] f32
    const short* __restrict__ zbuf,  // 1 KB zeros (border rows)
    short* __restrict__ hout,        // PRE-SWIZZLED store
    float* __restrict__ cout) {
  const int b = blockIdx.x;        // 0..31 batch (fast dim -> XCD spread)
  const int y = blockIdx.y;        // 0..63 row   (same-b rows co-XCD)
  const int tid = threadIdx.x;
  const int lane = tid & 63;
  const int wv = tid >> 6;         // 0..7
  const int wnf = wv & 3;          // oc slice within each gate
  const int whalf = wv >> 2;       // 0..1 px half
  const int col = lane & 15;
  const int quad = lane >> 4;

  __shared__ short As3[3][8192];   // 3 x 16 KB gate-pair buffers
  __shared__ short Bs[3 * 66 * 64];
  __shared__ float xs[3][64];

  const short* hb = hin + (size_t)b * (HW * 64);
  // ---- DMA B halo: rows y-1..y+1; wave wv covers px 8wv..8wv+7 per row ----
#pragma unroll
  for (int r = 0; r < 3; ++r) {
    const int py = y - 1 + r;
    const short* src = (py >= 0 && py < 64)
        ? hb + ((py * 64 + 8 * wv + (lane >> 3)) * 64 + (lane & 7) * 8)
        : zbuf + lane * 8;
    dma16(src, &Bs[(r * 66 + 8 * wv + 1) * 64]);
  }
  // ---- DMA A: loads(0) -> buf0, loads(1) -> buf1 ----
#pragma unroll
  for (int k = 0; k < 2; ++k) {
    const short* src = W + (k >> 1) * 16384 + (k & 1) * 8192;
    dma16(src + (wv * 64 + lane) * 8, &As3[k][wv * 64 * 8]);
    dma16(src + (512 + wv * 64 + lane) * 8, &As3[k][(512 + wv * 64) * 8]);
  }
  // ---- zero x-border slots 0 and 65: 3 rows x 2 x 8 chunks ----
  if (tid < 48) {
    const int r = tid >> 4;
    const int s = ((tid >> 3) & 1) * 65;
    const int ch0 = (tid & 7) * 8;
    bf16x8 z = {0, 0, 0, 0, 0, 0, 0, 0};
    *reinterpret_cast<bf16x8*>(&Bs[(r * 66 + s) * 64 + ch0]) = z;
  }
  if (HAS_X) {
    if (tid < 192) {
      const float* xb = xpl + (size_t)b * (12 * HW);
      const int r = tid >> 6, cx = tid & 63;
      const int py = y - 1 + r;
      xs[r][cx] = (py >= 0 && py < 64) ? xb[py * 64 + cx] : 0.f;
    }
  }
  // B halo + loads(0) complete; loads(1) (2 newest) may stay in flight.
  asm volatile("s_waitcnt vmcnt(2) lgkmcnt(0)" ::: "memory");
  __builtin_amdgcn_s_barrier();

  f32x4 acc[4][2];  // [gate][local n-tile]
#pragma unroll
  for (int g = 0; g < 4; ++g) {
    const int oc0 = g * 64 + wnf * 16 + quad * 4;
#pragma unroll
    for (int nt = 0; nt < 2; ++nt)
#pragma unroll
      for (int r = 0; r < 4; ++r) acc[g][nt][r] = bias[oc0 + r];
  }

  if (HAS_X) {  // vectorized: wx is [9][256] -> f32x4 per (tap, gate)
#pragma unroll
    for (int tap = 0; tap < 9; ++tap) {
      float xv[2];
#pragma unroll
      for (int nt = 0; nt < 2; ++nt) {
        const int pxx = whalf * 32 + nt * 16 + col + (tap % 3) - 1;
        xv[nt] = (pxx >= 0 && pxx < 64) ? xs[tap / 3][pxx] : 0.f;
      }
      const float* wt = wx + tap * 256;
#pragma unroll
      for (int g = 0; g < 4; ++g) {
        const int oc0 = g * 64 + wnf * 16 + quad * 4;
        const f32x4 w4 = *reinterpret_cast<const f32x4*>(wt + oc0);
#pragma unroll
        for (int nt = 0; nt < 2; ++nt)
#pragma unroll
          for (int r = 0; r < 4; ++r)
            acc[g][nt][r] = fmaf(xv[nt], w4[r], acc[g][nt][r]);
      }
    }
  }

  // ---- main loop: 18*REPS phases; A rotates over 3 buffers; loads(k+2)
  // issued at phase k; counted vmcnt(2); drain only at the final phase. ----
  const int axr = (col & 7) << 3;
#pragma unroll
  for (int k = 0; k < 18 * REPS; ++k) {
    const int pk = k % 18;
    const int tap = pk >> 1, gp = pk & 1, p = k % 3;
    if (k > 0) {
      if (k == 18 * REPS - 1)
        asm volatile("s_waitcnt vmcnt(0)" ::: "memory");
      else
        asm volatile("s_waitcnt vmcnt(2)" ::: "memory");
      __builtin_amdgcn_s_barrier();
    }
    if (k + 2 < 18 * REPS) {  // DMA phase k+2 into buffer freed by k-1
      const int nk = (k + 2) % 18;
      const short* src = W + (nk >> 1) * 16384 + (nk & 1) * 8192;
      dma16(src + (wv * 64 + lane) * 8, &As3[(k + 2) % 3][wv * 64 * 8]);
      dma16(src + (512 + wv * 64 + lane) * 8,
            &As3[(k + 2) % 3][(512 + wv * 64) * 8]);
    }
    const int hr = tap / 3;
    const int sb = col + tap % 3;        // slot base (= px+dx+1 mod offsets)
    const int sx = (sb & 7) << 3;        // whalf*32 / nt*16 keep low 3 bits
    const int srow = (hr * 66 + whalf * 32 + sb) * 64;
#pragma unroll
    for (int kc = 0; kc < 2; ++kc) {
      const int chb = kc * 32 + quad * 8;
      const int abase = ((wnf * 16 + col) * 64 + chb) ^ axr;
      const int bbase = (srow + chb) ^ sx;
      bf16x8 a0 = *reinterpret_cast<const bf16x8*>(&As3[p][abase]);
      bf16x8 a1 = *reinterpret_cast<const bf16x8*>(&As3[p][abase + 4096]);
      bf16x8 b0 = *reinterpret_cast<const bf16x8*>(&Bs[bbase]);
      bf16x8 b1 = *reinterpret_cast<const bf16x8*>(&Bs[bbase + 1024]);
      __builtin_amdgcn_s_setprio(1);
      acc[gp * 2][0] = __builtin_amdgcn_mfma_f32_16x16x32_bf16(a0, b0, acc[gp * 2][0], 0, 0, 0);
      acc[gp * 2][1] = __builtin_amdgcn_mfma_f32_16x16x32_bf16(a0, b1, acc[gp * 2][1], 0, 0, 0);
      acc[gp * 2 + 1][0] = __builtin_amdgcn_mfma_f32_16x16x32_bf16(a1, b0, acc[gp * 2 + 1][0], 0, 0, 0);
      acc[gp * 2 + 1][1] = __builtin_amdgcn_mfma_f32_16x16x32_bf16(a1, b1, acc[gp * 2 + 1][1], 0, 0, 0);
      __builtin_amdgcn_s_setprio(0);
    }
  }

  // ---- in-register epilogue; h stored PRE-SWIZZLED ----
  const int nf0 = wnf * 16 + quad * 4;
#pragma unroll
  for (int nt = 0; nt < 2; ++nt) {
    const int px = whalf * 32 + nt * 16 + col;
    const int swz = ((px + 1) & 7) << 3;
    const size_t pix = (size_t)b * HW + y * 64 + px;
    f32x4 cold = *reinterpret_cast<const f32x4*>(cin + pix * 64 + nf0);
    f32x4 cnew;
    short hnew[4];
#pragma unroll
    for (int r = 0; r < 4; ++r) {
      float i_ = fsig(acc[0][nt][r]);
      float f_ = fsig(acc[1][nt][r]);
      float o_ = fsig(acc[2][nt][r]);
      float g_ = ftanh(acc[3][nt][r]);
      float cn = fmaf(f_, cold[r], i_ * g_);
      cnew[r] = cn;
      hnew[r] = f2bf(o_ * ftanh(cn));
    }
    if constexpr (SINK) {
      float s = cnew[0] + cnew[1] + cnew[2] + cnew[3] +
                (float)hnew[0] + (float)hnew[1] + (float)hnew[2] + (float)hnew[3];
      asm volatile("" ::"v"(s));  // keep math live, no stores (rule #17)
    } else {
      *reinterpret_cast<f32x4*>(cout + pix * 64 + nf0) = cnew;
      short4 hv = make_short4(hnew[0], hnew[1], hnew[2], hnew[3]);
      *reinterpret_cast<short4*>(hout + pix * 64 + (nf0 ^ swz)) = hv;
    }
  }
}

// head: y[b,t,pix] = b_cnn + sum_{f,tap} wc2[tap][f] * h[pix+tap][f]
// h is pre-swizzled: group f8 lives at group f8 ^ ((px+1)&7)
__global__ __launch_bounds__(256) void head_k(const short* __restrict__ h,
                                              const float* __restrict__ wc2,
                                              const float* __restrict__ bc,
                                              float* __restrict__ yout, int t) {
  const int tid = blockIdx.x * 256 + threadIdx.x;  // 131072 threads
  const int pix = tid & 4095;
  const int b = tid >> 12;
  const int x0 = pix & 63, y0 = pix >> 6;
  float acc = bc[0];
  const short* hb = h + (size_t)b * (HW * 64);
#pragma unroll
  for (int tap = 0; tap < 9; ++tap) {
    const int yy = y0 + tap / 3 - 1, xx = x0 + (tap % 3) - 1;
    if (yy < 0 || yy > 63 || xx < 0 || xx > 63) continue;
    const short* hp = hb + (yy * 64 + xx) * 64;
    const int sw8 = (xx + 1) & 7;
    const float* wp = wc2 + tap * 64;
#pragma unroll
    for (int f8 = 0; f8 < 8; ++f8) {
      bf16x8 v = *reinterpret_cast<const bf16x8*>(hp + ((f8 ^ sw8) * 8));
#pragma unroll
      for (int j = 0; j < 8; ++j) acc = fmaf(wp[f8 * 8 + j], bf2f(v[j]), acc);
    }
  }
  yout[(size_t)(b * 12 + t) * HW + pix] = acc;
}

// encoder-vector output: transpose swizzled [b][pix][ch] bf16 -> [b][ch][pix] f32
__global__ __launch_bounds__(256) void ev_out_k(const short* __restrict__ h,
                                                float* __restrict__ out) {
  __shared__ float tl[64][65];
  const int b = blockIdx.y, pg = blockIdx.x;
  const int p0 = pg * 64;
  {
    const int pixl = threadIdx.x >> 2, c0 = (threadIdx.x & 3) * 16;
    const int sw8 = (pixl + 1) & 7;   // px = pixl (p0 multiple of 64)
    const short* hp = h + ((size_t)b * HW + p0 + pixl) * 64;
#pragma unroll
    for (int gi = 0; gi < 2; ++gi) {
      const int grp = (c0 >> 3) + gi;
      bf16x8 v = *reinterpret_cast<const bf16x8*>(hp + ((grp ^ sw8) * 8));
#pragma unroll
      for (int j = 0; j < 8; ++j) tl[pixl][grp * 8 + j] = bf2f(v[j]);
    }
  }
  __syncthreads();
  {
    const int ch = threadIdx.x >> 2, q0 = (threadIdx.x & 3) * 16;
    float* op = out + ((size_t)b * 64 + ch) * (size_t)HW + p0 + q0;
#pragma unroll
    for (int i = 0; i < 16; ++i) op[i] = tl[q0 + i][ch];
  }
}

// W_enc [256][65][3][3] f32 -> Wh bf16 [9][256][64] SWIZZLED (^(oc&7)<<3)
// + wx f32 [9][256] (tap-major for vectorized f32x4 loads)
__global__ __launch_bounds__(256) void reo_enc_k(const float* __restrict__ src,
                                                 short* __restrict__ Wh,
                                                 float* __restrict__ wx) {
  const int idx = blockIdx.x * 256 + threadIdx.x;
  if (idx < 9 * 256 * 64) {
    const int tap = idx >> 14, oc = (idx >> 6) & 255, c = idx & 63;
    const int dst = tap * 16384 + (((oc * 64) + c) ^ ((oc & 7) << 3));
    Wh[dst] = f2bf(src[(oc * 65 + (c + 1)) * 9 + tap]);
  }
  if (idx < 256 * 9) {
    const int tap = idx >> 8, oc = idx & 255;  // wx[tap][oc]
    wx[idx] = src[(oc * 65 + 0) * 9 + tap];
  }
}

// W_dec [256][128][3][3] f32 -> Wx bf16 [9][256][64], Wsum bf16, both swizzled
__global__ __launch_bounds__(256) void reo_dec_k(const float* __restrict__ src,
                                                 short* __restrict__ Wx,
                                                 short* __restrict__ Ws) {
  const int idx = blockIdx.x * 256 + threadIdx.x;
  if (idx >= 9 * 256 * 64) return;
  const int tap = idx >> 14, oc = (idx >> 6) & 255, c = idx & 63;
  const int dst = tap * 16384 + (((oc * 64) + c) ^ ((oc & 7) << 3));
  const float a = src[(oc * 128 + c) * 9 + tap];
  const float b = src[(oc * 128 + 64 + c) * 9 + tap];
  Wx[dst] = f2bf(a);
  Ws[dst] = f2bf(a + b);
}

// W_cnn [64][9] f32 -> [9][64] f32
__global__ __launch_bounds__(256) void reo_cnn_k(const float* __restrict__ src,
                                                 float* __restrict__ wc2) {
  const int idx = blockIdx.x * 256 + threadIdx.x;
  if (idx >= 576) return;
  wc2[idx] = src[(idx % 64) * 9 + (idx / 64)];
}

extern "C" void kernel_launch(void* const* d_in, const int* in_sizes, int n_in,
                              void* d_out, int out_size, void* d_ws, size_t ws_size,
                              hipStream_t stream) {
  const float* x = (const float*)d_in[0];       // [32,12,1,64,64] f32
  const float* W_enc = (const float*)d_in[2];
  const float* b_enc = (const float*)d_in[3];
  const float* W_dec = (const float*)d_in[4];
  const float* b_dec = (const float*)d_in[5];
  const float* W_cnn = (const float*)d_in[6];
  const float* b_cnn = (const float*)d_in[7];
  float* out = (float*)d_out;
  float* out_y = out;                 // [32][12][4096]
  float* out_ev = out + 1572864;      // [32][64][4096]

  float* ws = (float*)d_ws;
  float* cA = ws;                                // 8388608 f
  float* cB = cA + 8388608;                      // 8388608 f
  short* hA = (short*)(cB + 8388608);            // 8388608 sh
  short* hB = hA + 8388608;                      // 8388608 sh
  short* WEh = hB + 8388608;                     // 147456 sh
  short* WDx = WEh + 147456;                     // 147456 sh
  short* WDs = WDx + 147456;                     // 147456 sh
  float* wx = (float*)(WDs + 147456);            // 2304 f
  float* wc2 = wx + 2304;                        // 576 f
  short* zb = (short*)(wc2 + 576);               // 512 sh zeros (~101 MB total)

  reo_enc_k<<<(147456 + 255) / 256, 256, 0, stream>>>(W_enc, WEh, wx);
  reo_dec_k<<<(147456 + 255) / 256, 256, 0, stream>>>(W_dec, WDx, WDs);
  reo_cnn_k<<<3, 256, 0, stream>>>(W_cnn, wc2);

  hipMemsetAsync(hA, 0, 8388608 * sizeof(short), stream);
  hipMemsetAsync(cA, 0, 8388608 * sizeof(float), stream);
  hipMemsetAsync(zb, 0, 512 * sizeof(short), stream);

  dim3 gridL(32, 64), blkL(512);   // x=batch (XCD-fast), y=row; 1 row/block
  dim3 gridE(64, 32), blkE(256);
  short *ha = hA, *hb = hB;
  float *ca = cA, *cb = cB;

  // ---- DIAGNOSTIC: phase-loop x2, stores sunk. loop_time = abl - enc ----
  lstm_mfma_k<true, 2, true><<<gridL, blkL, 0, stream>>>(
      hA, WEh, wx, x, b_enc, cA, zb, hB, cB);

  // ---- encoder ----
  for (int t = 0; t < 12; ++t) {
    lstm_mfma_k<true, 1, false><<<gridL, blkL, 0, stream>>>(
        ha, WEh, wx, x + t * HW, b_enc, ca, zb, hb, cb);
    { short* tm = ha; ha = hb; hb = tm; }
    { float* tm = ca; ca = cb; cb = tm; }
  }
  // ha = h_enc (swizzled) -> output 1 (un-swizzled transpose to [b][ch][pix])
  ev_out_k<<<gridE, blkE, 0, stream>>>(ha, out_ev);

  // fresh zero c for decoder
  hipMemsetAsync(cb, 0, 8388608 * sizeof(float), stream);
  { float* tm = ca; ca = cb; cb = tm; }  // ca = zeroed c

  // ---- decoder ----
  for (int t = 0; t < 12; ++t) {
    lstm_mfma_k<false, 1, false><<<gridL, blkL, 0, stream>>>(
        ha, (t == 0) ? WDx : WDs, nullptr, nullptr, b_dec, ca, zb, hb, cb);
    { short* tm = ha; ha = hb; hb = tm; }
    { float* tm = ca; ca = cb; cb = tm; }
    head_k<<<512, 256, 0, stream>>>(ha, wc2, b_cnn, out_y, t);
  }
}

// Round 10
// 1814.730 us; speedup vs baseline: 1.1427x; 1.1427x over previous
//
#include <hip/hip_runtime.h>
#include <hip/hip_bf16.h>

// EncoderDecoderConvLSTM — Round 20: overhead attack.
// R19 ablation: loop = ~35us of each ~94us lstm dispatch -> non-loop (staging
// prologue, epilogue, launch ramp/tail, serial head_k dispatches) dominates.
// Changes: (1) head fused into decoder lstm t=1..11 as 256 extra blocks
// (grid 36x64) reading the same hin -> 11 fewer serial dispatches; (2)
// encoder t=0 HAS_H=false fast path (h==0: skip halo+loop entirely) and no
// h/c memsets; (3) cin==null -> cold=0 (kills decoder c memset); (4) B-read
// hoist: Bs is immutable after prologue, so each tap's 4 B-frags are read
// once at gp=0 and held in regs across the gp=1 barrier (wave LDS traffic
// 144->108 KB, loop is at the LDS-BW floor); (5) diag dispatch removed.
// Else identical to R18/R19: DMA staging, 3-buf counted-vmcnt A pipeline,
// pre-swizzled W (^(oc&7)<<3) and h (^((px+1)&7)<<3), zero-page border.

#define HW 4096
#define NF 64

typedef __attribute__((ext_vector_type(8))) short bf16x8;
typedef __attribute__((ext_vector_type(4))) float f32x4;

__device__ __forceinline__ float fsig(float v) {
  return __builtin_amdgcn_rcpf(1.f + __expf(-v));
}
__device__ __forceinline__ float ftanh(float v) {
  float vc = fminf(fmaxf(v, -15.f), 15.f);
  float e = __expf(2.f * vc);
  return (e - 1.f) * __builtin_amdgcn_rcpf(e + 1.f);
}
__device__ __forceinline__ float bf2f(short s) {
  union { unsigned u; float f; } a;
  a.u = ((unsigned)(unsigned short)s) << 16;
  return a.f;
}
__device__ __forceinline__ short f2bf(float f) {  // RNE
  union { float f; unsigned u; } a;
  a.f = f;
  unsigned r = (a.u + 0x7fff + ((a.u >> 16) & 1)) >> 16;
  return (short)r;
}
// async 16B/lane global->LDS; lds base must be wave-uniform
__device__ __forceinline__ void dma16(const short* g, short* l) {
  __builtin_amdgcn_global_load_lds(
      (const __attribute__((address_space(1))) char*)g,
      (__attribute__((address_space(3))) char*)l, 16, 0, 0);
}

// 8 waves: wnf = wv&3 (16-oc slice per gate), whalf = wv>>2 (px half).
// LDS: As3[3][8192] rotating gate-pair buffers (pre-swizzled W, linear DMA),
// Bs[3][66][64] halo (slot s = px+1; slots 0/65 zero; content swizzled
// ^(s&7)<<3 via pre-swizzled h_sw), xs[3][64].
template <bool HAS_X, bool HAS_H, bool FUSE_HEAD>
__global__ __launch_bounds__(512) void lstm_mfma_k(
    const short* __restrict__ hin,   // [32][4096][64] bf16, PRE-SWIZZLED
    const short* __restrict__ W,     // [9][256][64] bf16, pre-swizzled
    const float* __restrict__ wx,    // [9][256] f32 (x-part) or null
    const float* __restrict__ xpl,   // x + t*HW (batch stride 12*HW) or null
    const float* __restrict__ bias,  // [256] f32
    const float* __restrict__ cin,   // [32][4096][64] f32 or null (c==0)
    const short* __restrict__ zbuf,  // 1 KB zeros (border rows)
    short* __restrict__ hout,        // PRE-SWIZZLED store
    float* __restrict__ cout,
    const float* __restrict__ wc2,   // [9][64] f32 (head) or null
    const float* __restrict__ bcnn,  // [1] f32 (head) or null
    float* __restrict__ yout,        // [32][12][4096] or null
    int th) {                        // head time index
  if (FUSE_HEAD) {
    if (blockIdx.x >= 32) {  // ---- fused head: y[th] from hin ----
      const int f = ((blockIdx.x - 32) * 64 + blockIdx.y) * 512 + threadIdx.x;
      const int pix = f & 4095;
      const int b = f >> 12;
      const int x0 = pix & 63, y0 = pix >> 6;
      float acc = bcnn[0];
      const short* hb = hin + (size_t)b * (HW * 64);
#pragma unroll
      for (int tap = 0; tap < 9; ++tap) {
        const int yy = y0 + tap / 3 - 1, xx = x0 + (tap % 3) - 1;
        if (yy < 0 || yy > 63 || xx < 0 || xx > 63) continue;
        const short* hp = hb + (yy * 64 + xx) * 64;
        const int sw8 = (xx + 1) & 7;
        const float* wp = wc2 + tap * 64;
#pragma unroll
        for (int f8 = 0; f8 < 8; ++f8) {
          bf16x8 v = *reinterpret_cast<const bf16x8*>(hp + ((f8 ^ sw8) * 8));
#pragma unroll
          for (int j = 0; j < 8; ++j)
            acc = fmaf(wp[f8 * 8 + j], bf2f(v[j]), acc);
        }
      }
      yout[(size_t)(b * 12 + th) * HW + pix] = acc;
      return;
    }
  }
  const int b = blockIdx.x;        // 0..31 batch (fast dim -> XCD spread)
  const int y = blockIdx.y;        // 0..63 row   (same-b rows co-XCD)
  const int tid = threadIdx.x;
  const int lane = tid & 63;
  const int wv = tid >> 6;         // 0..7
  const int wnf = wv & 3;          // oc slice within each gate
  const int whalf = wv >> 2;       // 0..1 px half
  const int col = lane & 15;
  const int quad = lane >> 4;

  __shared__ short As3[3][8192];   // 3 x 16 KB gate-pair buffers
  __shared__ short Bs[3 * 66 * 64];
  __shared__ float xs[3][64];

  if (HAS_H) {
    const short* hb = hin + (size_t)b * (HW * 64);
    // ---- DMA B halo: rows y-1..y+1; wave wv covers px 8wv..8wv+7 ----
#pragma unroll
    for (int r = 0; r < 3; ++r) {
      const int py = y - 1 + r;
      const short* src = (py >= 0 && py < 64)
          ? hb + ((py * 64 + 8 * wv + (lane >> 3)) * 64 + (lane & 7) * 8)
          : zbuf + lane * 8;
      dma16(src, &Bs[(r * 66 + 8 * wv + 1) * 64]);
    }
    // ---- DMA A: loads(0) -> buf0, loads(1) -> buf1 ----
#pragma unroll
    for (int k = 0; k < 2; ++k) {
      const short* src = W + (k >> 1) * 16384 + (k & 1) * 8192;
      dma16(src + (wv * 64 + lane) * 8, &As3[k][wv * 64 * 8]);
      dma16(src + (512 + wv * 64 + lane) * 8, &As3[k][(512 + wv * 64) * 8]);
    }
    // ---- zero x-border slots 0 and 65: 3 rows x 2 x 8 chunks ----
    if (tid < 48) {
      const int r = tid >> 4;
      const int s = ((tid >> 3) & 1) * 65;
      const int ch0 = (tid & 7) * 8;
      bf16x8 z = {0, 0, 0, 0, 0, 0, 0, 0};
      *reinterpret_cast<bf16x8*>(&Bs[(r * 66 + s) * 64 + ch0]) = z;
    }
  }
  if (HAS_X) {
    if (tid < 192) {
      const float* xb = xpl + (size_t)b * (12 * HW);
      const int r = tid >> 6, cx = tid & 63;
      const int py = y - 1 + r;
      xs[r][cx] = (py >= 0 && py < 64) ? xb[py * 64 + cx] : 0.f;
    }
  }
  if (HAS_H) {
    // B halo + loads(0) complete; loads(1) (2 newest) may stay in flight.
    asm volatile("s_waitcnt vmcnt(2) lgkmcnt(0)" ::: "memory");
    __builtin_amdgcn_s_barrier();
  } else {
    __syncthreads();  // xs only
  }

  f32x4 acc[4][2];  // [gate][local n-tile]
#pragma unroll
  for (int g = 0; g < 4; ++g) {
    const int oc0 = g * 64 + wnf * 16 + quad * 4;
#pragma unroll
    for (int nt = 0; nt < 2; ++nt)
#pragma unroll
      for (int r = 0; r < 4; ++r) acc[g][nt][r] = bias[oc0 + r];
  }

  if (HAS_X) {  // vectorized: wx is [9][256] -> f32x4 per (tap, gate)
#pragma unroll
    for (int tap = 0; tap < 9; ++tap) {
      float xv[2];
#pragma unroll
      for (int nt = 0; nt < 2; ++nt) {
        const int pxx = whalf * 32 + nt * 16 + col + (tap % 3) - 1;
        xv[nt] = (pxx >= 0 && pxx < 64) ? xs[tap / 3][pxx] : 0.f;
      }
      const float* wt = wx + tap * 256;
#pragma unroll
      for (int g = 0; g < 4; ++g) {
        const int oc0 = g * 64 + wnf * 16 + quad * 4;
        const f32x4 w4 = *reinterpret_cast<const f32x4*>(wt + oc0);
#pragma unroll
        for (int nt = 0; nt < 2; ++nt)
#pragma unroll
          for (int r = 0; r < 4; ++r)
            acc[g][nt][r] = fmaf(xv[nt], w4[r], acc[g][nt][r]);
      }
    }
  }

  if (HAS_H) {
    // ---- main loop: 18 phases (tap x gate-pair); A rotates 3 buffers,
    // loads(k+2) issued at k, counted vmcnt(2). B-frags read ONCE per tap
    // (at gp=0; Bs is immutable) and held in regs across the gp=1 barrier.
    const int axr = (col & 7) << 3;
    bf16x8 bh00, bh01, bh10, bh11;  // [kc][nt], live across gp phases
#pragma unroll
    for (int k = 0; k < 18; ++k) {
      const int tap = k >> 1, gp = k & 1, p = k % 3;
      if (k > 0) {
        if (k == 17)
          asm volatile("s_waitcnt vmcnt(0)" ::: "memory");
        else
          asm volatile("s_waitcnt vmcnt(2)" ::: "memory");
        __builtin_amdgcn_s_barrier();
      }
      if (k + 2 < 18) {  // DMA phase k+2 into buffer freed by k-1
        const int nk = k + 2;
        const short* src = W + (nk >> 1) * 16384 + (nk & 1) * 8192;
        dma16(src + (wv * 64 + lane) * 8, &As3[nk % 3][wv * 64 * 8]);
        dma16(src + (512 + wv * 64 + lane) * 8,
              &As3[nk % 3][(512 + wv * 64) * 8]);
      }
      if (gp == 0) {  // read this tap's 4 B-frags once
        const int hr = tap / 3;
        const int sb = col + tap % 3;
        const int sx = (sb & 7) << 3;
        const int srow = (hr * 66 + whalf * 32 + sb) * 64;
        const int b0 = (srow + quad * 8) ^ sx;
        const int b1 = (srow + 32 + quad * 8) ^ sx;
        bh00 = *reinterpret_cast<const bf16x8*>(&Bs[b0]);
        bh01 = *reinterpret_cast<const bf16x8*>(&Bs[b0 + 1024]);
        bh10 = *reinterpret_cast<const bf16x8*>(&Bs[b1]);
        bh11 = *reinterpret_cast<const bf16x8*>(&Bs[b1 + 1024]);
      }
#pragma unroll
      for (int kc = 0; kc < 2; ++kc) {
        const int chb = kc * 32 + quad * 8;
        const int abase = ((wnf * 16 + col) * 64 + chb) ^ axr;
        bf16x8 a0 = *reinterpret_cast<const bf16x8*>(&As3[p][abase]);
        bf16x8 a1 = *reinterpret_cast<const bf16x8*>(&As3[p][abase + 4096]);
        const bf16x8 bb0 = kc ? bh10 : bh00;
        const bf16x8 bb1 = kc ? bh11 : bh01;
        __builtin_amdgcn_s_setprio(1);
        acc[gp * 2][0] = __builtin_amdgcn_mfma_f32_16x16x32_bf16(a0, bb0, acc[gp * 2][0], 0, 0, 0);
        acc[gp * 2][1] = __builtin_amdgcn_mfma_f32_16x16x32_bf16(a0, bb1, acc[gp * 2][1], 0, 0, 0);
        acc[gp * 2 + 1][0] = __builtin_amdgcn_mfma_f32_16x16x32_bf16(a1, bb0, acc[gp * 2 + 1][0], 0, 0, 0);
        acc[gp * 2 + 1][1] = __builtin_amdgcn_mfma_f32_16x16x32_bf16(a1, bb1, acc[gp * 2 + 1][1], 0, 0, 0);
        __builtin_amdgcn_s_setprio(0);
      }
    }
  }

  // ---- in-register epilogue; h stored PRE-SWIZZLED; cin==null -> c=0 ----
  const int nf0 = wnf * 16 + quad * 4;
#pragma unroll
  for (int nt = 0; nt < 2; ++nt) {
    const int px = whalf * 32 + nt * 16 + col;
    const int swz = ((px + 1) & 7) << 3;
    const size_t pix = (size_t)b * HW + y * 64 + px;
    f32x4 cold = {0.f, 0.f, 0.f, 0.f};
    if (cin) cold = *reinterpret_cast<const f32x4*>(cin + pix * 64 + nf0);
    f32x4 cnew;
    short hnew[4];
#pragma unroll
    for (int r = 0; r < 4; ++r) {
      float i_ = fsig(acc[0][nt][r]);
      float f_ = fsig(acc[1][nt][r]);
      float o_ = fsig(acc[2][nt][r]);
      float g_ = ftanh(acc[3][nt][r]);
      float cn = fmaf(f_, cold[r], i_ * g_);
      cnew[r] = cn;
      hnew[r] = f2bf(o_ * ftanh(cn));
    }
    *reinterpret_cast<f32x4*>(cout + pix * 64 + nf0) = cnew;
    short4 hv = make_short4(hnew[0], hnew[1], hnew[2], hnew[3]);
    *reinterpret_cast<short4*>(hout + pix * 64 + (nf0 ^ swz)) = hv;
  }
}

// standalone head (last decoder step): y[b,t,pix] from pre-swizzled h
__global__ __launch_bounds__(256) void head_k(const short* __restrict__ h,
                                              const float* __restrict__ wc2,
                                              const float* __restrict__ bc,
                                              float* __restrict__ yout, int t) {
  const int tid = blockIdx.x * 256 + threadIdx.x;  // 131072 threads
  const int pix = tid & 4095;
  const int b = tid >> 12;
  const int x0 = pix & 63, y0 = pix >> 6;
  float acc = bc[0];
  const short* hb = h + (size_t)b * (HW * 64);
#pragma unroll
  for (int tap = 0; tap < 9; ++tap) {
    const int yy = y0 + tap / 3 - 1, xx = x0 + (tap % 3) - 1;
    if (yy < 0 || yy > 63 || xx < 0 || xx > 63) continue;
    const short* hp = hb + (yy * 64 + xx) * 64;
    const int sw8 = (xx + 1) & 7;
    const float* wp = wc2 + tap * 64;
#pragma unroll
    for (int f8 = 0; f8 < 8; ++f8) {
      bf16x8 v = *reinterpret_cast<const bf16x8*>(hp + ((f8 ^ sw8) * 8));
#pragma unroll
      for (int j = 0; j < 8; ++j) acc = fmaf(wp[f8 * 8 + j], bf2f(v[j]), acc);
    }
  }
  yout[(size_t)(b * 12 + t) * HW + pix] = acc;
}

// encoder-vector output: transpose swizzled [b][pix][ch] bf16 -> [b][ch][pix] f32
__global__ __launch_bounds__(256) void ev_out_k(const short* __restrict__ h,
                                                float* __restrict__ out) {
  __shared__ float tl[64][65];
  const int b = blockIdx.y, pg = blockIdx.x;
  const int p0 = pg * 64;
  {
    const int pixl = threadIdx.x >> 2, c0 = (threadIdx.x & 3) * 16;
    const int sw8 = (pixl + 1) & 7;   // px = pixl (p0 multiple of 64)
    const short* hp = h + ((size_t)b * HW + p0 + pixl) * 64;
#pragma unroll
    for (int gi = 0; gi < 2; ++gi) {
      const int grp = (c0 >> 3) + gi;
      bf16x8 v = *reinterpret_cast<const bf16x8*>(hp + ((grp ^ sw8) * 8));
#pragma unroll
      for (int j = 0; j < 8; ++j) tl[pixl][grp * 8 + j] = bf2f(v[j]);
    }
  }
  __syncthreads();
  {
    const int ch = threadIdx.x >> 2, q0 = (threadIdx.x & 3) * 16;
    float* op = out + ((size_t)b * 64 + ch) * (size_t)HW + p0 + q0;
#pragma unroll
    for (int i = 0; i < 16; ++i) op[i] = tl[q0 + i][ch];
  }
}

// W_enc [256][65][3][3] f32 -> Wh bf16 [9][256][64] SWIZZLED (^(oc&7)<<3)
// + wx f32 [9][256] (tap-major for vectorized f32x4 loads)
__global__ __launch_bounds__(256) void reo_enc_k(const float* __restrict__ src,
                                                 short* __restrict__ Wh,
                                                 float* __restrict__ wx) {
  const int idx = blockIdx.x * 256 + threadIdx.x;
  if (idx < 9 * 256 * 64) {
    const int tap = idx >> 14, oc = (idx >> 6) & 255, c = idx & 63;
    const int dst = tap * 16384 + (((oc * 64) + c) ^ ((oc & 7) << 3));
    Wh[dst] = f2bf(src[(oc * 65 + (c + 1)) * 9 + tap]);
  }
  if (idx < 256 * 9) {
    const int tap = idx >> 8, oc = idx & 255;  // wx[tap][oc]
    wx[idx] = src[(oc * 65 + 0) * 9 + tap];
  }
}

// W_dec [256][128][3][3] f32 -> Wx bf16 [9][256][64], Wsum bf16, both swizzled
__global__ __launch_bounds__(256) void reo_dec_k(const float* __restrict__ src,
                                                 short* __restrict__ Wx,
                                                 short* __restrict__ Ws) {
  const int idx = blockIdx.x * 256 + threadIdx.x;
  if (idx >= 9 * 256 * 64) return;
  const int tap = idx >> 14, oc = (idx >> 6) & 255, c = idx & 63;
  const int dst = tap * 16384 + (((oc * 64) + c) ^ ((oc & 7) << 3));
  const float a = src[(oc * 128 + c) * 9 + tap];
  const float b = src[(oc * 128 + 64 + c) * 9 + tap];
  Wx[dst] = f2bf(a);
  Ws[dst] = f2bf(a + b);
}

// W_cnn [64][9] f32 -> [9][64] f32
__global__ __launch_bounds__(256) void reo_cnn_k(const float* __restrict__ src,
                                                 float* __restrict__ wc2) {
  const int idx = blockIdx.x * 256 + threadIdx.x;
  if (idx >= 576) return;
  wc2[idx] = src[(idx % 64) * 9 + (idx / 64)];
}

extern "C" void kernel_launch(void* const* d_in, const int* in_sizes, int n_in,
                              void* d_out, int out_size, void* d_ws, size_t ws_size,
                              hipStream_t stream) {
  const float* x = (const float*)d_in[0];       // [32,12,1,64,64] f32
  const float* W_enc = (const float*)d_in[2];
  const float* b_enc = (const float*)d_in[3];
  const float* W_dec = (const float*)d_in[4];
  const float* b_dec = (const float*)d_in[5];
  const float* W_cnn = (const float*)d_in[6];
  const float* b_cnn = (const float*)d_in[7];
  float* out = (float*)d_out;
  float* out_y = out;                 // [32][12][4096]
  float* out_ev = out + 1572864;      // [32][64][4096]

  float* ws = (float*)d_ws;
  float* cA = ws;                                // 8388608 f
  float* cB = cA + 8388608;                      // 8388608 f
  short* hA = (short*)(cB + 8388608);            // 8388608 sh
  short* hB = hA + 8388608;                      // 8388608 sh
  short* WEh = hB + 8388608;                     // 147456 sh
  short* WDx = WEh + 147456;                     // 147456 sh
  short* WDs = WDx + 147456;                     // 147456 sh
  float* wx = (float*)(WDs + 147456);            // 2304 f
  float* wc2 = wx + 2304;                        // 576 f
  short* zb = (short*)(wc2 + 576);               // 512 sh zeros (~101 MB total)

  reo_enc_k<<<(147456 + 255) / 256, 256, 0, stream>>>(W_enc, WEh, wx);
  reo_dec_k<<<(147456 + 255) / 256, 256, 0, stream>>>(W_dec, WDx, WDs);
  reo_cnn_k<<<3, 256, 0, stream>>>(W_cnn, wc2);
  hipMemsetAsync(zb, 0, 512 * sizeof(short), stream);

  dim3 gridL(32, 64), blkL(512);   // x=batch (XCD-fast), y=row; 1 row/block
  dim3 gridF(36, 64);              // +4 columns = 256 fused-head blocks
  dim3 gridE(64, 32), blkE(256);

  // ---- encoder t=0: h==0, c==0 -> x-part only, no memsets needed ----
  lstm_mfma_k<true, false, false><<<gridL, blkL, 0, stream>>>(
      nullptr, WEh, wx, x, b_enc, nullptr, zb, hB, cB,
      nullptr, nullptr, nullptr, 0);
  short *ha = hB, *hb = hA;
  float *ca = cB, *cb = cA;

  // ---- encoder t=1..11 ----
  for (int t = 1; t < 12; ++t) {
    lstm_mfma_k<true, true, false><<<gridL, blkL, 0, stream>>>(
        ha, WEh, wx, x + t * HW, b_enc, ca, zb, hb, cb,
        nullptr, nullptr, nullptr, 0);
    { short* tm = ha; ha = hb; hb = tm; }
    { float* tm = ca; ca = cb; cb = tm; }
  }
  // ha = h_enc (swizzled) -> output 1 (un-swizzled transpose to [b][ch][pix])
  ev_out_k<<<gridE, blkE, 0, stream>>>(ha, out_ev);

  // ---- decoder t=0: c==0 via cin=null (no memset) ----
  lstm_mfma_k<false, true, false><<<gridL, blkL, 0, stream>>>(
      ha, WDx, nullptr, nullptr, b_dec, nullptr, zb, hb, cb,
      nullptr, nullptr, nullptr, 0);
  { short* tm = ha; ha = hb; hb = tm; }
  { float* tm = ca; ca = cb; cb = tm; }

  // ---- decoder t=1..11, head(outs[t-1]) fused (reads hin) ----
  for (int t = 1; t < 12; ++t) {
    lstm_mfma_k<false, true, true><<<gridF, blkL, 0, stream>>>(
        ha, WDs, nullptr, nullptr, b_dec, ca, zb, hb, cb,
        wc2, b_cnn, out_y, t - 1);
    { short* tm = ha; ha = hb; hb = tm; }
    { float* tm = ca; ca = cb; cb = tm; }
  }
  // ---- final head on outs[11] ----
  head_k<<<512, 256, 0, stream>>>(ha, wc2, b_cnn, out_y, 11);
}